// Round 1
// baseline (617.019 us; speedup 1.0000x reference)
//
#include <hip/hip_runtime.h>
#include <stdint.h>

typedef unsigned short u16;
using bf16x8 = __attribute__((ext_vector_type(8))) __bf16;
using f32x4  = __attribute__((ext_vector_type(4))) float;

#define MFMA16(a,b,c) __builtin_amdgcn_mfma_f32_16x16x32_bf16((a),(b),(c),0,0,0)

__device__ __forceinline__ u16 f2bf(float f) {
  union { float f; uint32_t u; } v; v.f = f;
  uint32_t r = v.u + 0x7FFFu + ((v.u >> 16) & 1u);
  return (u16)(r >> 16);
}

// async global->LDS, 16B per lane; lds ptr must be wave-uniform (HW: base + lane*16)
__device__ __forceinline__ void gload_lds16(const void* g, void* l) {
  typedef const __attribute__((address_space(1))) void* gp_t;
  typedef __attribute__((address_space(3))) void* lp_t;
  __builtin_amdgcn_global_load_lds((gp_t)(uintptr_t)g,
                                   (lp_t)(uint32_t)(uintptr_t)l, 16, 0, 0);
}

// ---------------- adaLN: cmod = silu(c) @ w_ada + b_ada  [8,6144] ----------------
__global__ __launch_bounds__(256)
void adaln_k(const float* __restrict__ c, const float* __restrict__ w,
             const float* __restrict__ bias, float* __restrict__ cmod) {
  __shared__ float sil[8192];
  for (int i = threadIdx.x; i < 8192; i += 256) {
    float v = c[i];
    sil[i] = v / (1.f + __expf(-v));
  }
  __syncthreads();
  int j = blockIdx.x * 256 + threadIdx.x;  // < 6144
  float acc[8] = {0,0,0,0,0,0,0,0};
  for (int k = 0; k < 1024; ++k) {
    float wv = w[(size_t)k * 6144 + j];
#pragma unroll
    for (int b = 0; b < 8; ++b) acc[b] += sil[b * 1024 + k] * wv;
  }
  float bb = bias[j];
#pragma unroll
  for (int b = 0; b < 8; ++b) cmod[(size_t)b * 6144 + j] = acc[b] + bb;
}

// ---------------- weight cast+transpose: in fp32 [K][N] -> out bf16 [N][K] ----------------
__global__ __launch_bounds__(256)
void tcast_k(const float* __restrict__ in, u16* __restrict__ out, int K, int N) {
  __shared__ u16 t[64][65];
  int n0 = blockIdx.x * 64, k0 = blockIdx.y * 64;
#pragma unroll
  for (int i = 0; i < 16; ++i) {
    int idx = i * 256 + threadIdx.x;
    int r = idx >> 6, cc = idx & 63;
    t[r][cc] = f2bf(in[(size_t)(k0 + r) * N + n0 + cc]);
  }
  __syncthreads();
#pragma unroll
  for (int i = 0; i < 16; ++i) {
    int idx = i * 256 + threadIdx.x;
    int r = idx >> 6, cc = idx & 63;
    out[(size_t)(n0 + r) * K + k0 + cc] = t[cc][r];
  }
}

// ---------------- LN + modulate -> bf16 ----------------
__global__ __launch_bounds__(256)
void lnmod_k(const float* __restrict__ x, const float* __restrict__ cmod,
             int shift_off, int scale_off, u16* __restrict__ out) {
  int row = blockIdx.x;           // 0..8191
  int b = row >> 10;
  const float4* xr = (const float4*)(x + (size_t)row * 1024);
  float4 v = xr[threadIdx.x];
  float s = v.x + v.y + v.z + v.w;
  float sq = v.x * v.x + v.y * v.y + v.z * v.z + v.w * v.w;
#pragma unroll
  for (int m = 32; m >= 1; m >>= 1) {
    s  += __shfl_xor(s, m);
    sq += __shfl_xor(sq, m);
  }
  __shared__ float ss[4], ssq[4];
  int wave = threadIdx.x >> 6, lane = threadIdx.x & 63;
  if (lane == 0) { ss[wave] = s; ssq[wave] = sq; }
  __syncthreads();
  s  = ss[0] + ss[1] + ss[2] + ss[3];
  sq = ssq[0] + ssq[1] + ssq[2] + ssq[3];
  float mean = s * (1.f / 1024.f);
  float var  = sq * (1.f / 1024.f) - mean * mean;
  float rstd = rsqrtf(var + 1e-6f);
  int col = threadIdx.x * 4;
  const float* sh = cmod + (size_t)b * 6144 + shift_off + col;
  const float* sc = cmod + (size_t)b * 6144 + scale_off + col;
  float xv[4] = {v.x, v.y, v.z, v.w};
  union { u16 o[4]; uint64_t u; } pk;
#pragma unroll
  for (int j = 0; j < 4; ++j)
    pk.o[j] = f2bf((xv[j] - mean) * rstd * (1.f + sc[j]) + sh[j]);
  *(uint64_t*)(out + (size_t)row * 1024 + col) = pk.u;
}

// ---------------- transpose V section of qkv -> vt[b,h,ch,s] bf16 ----------------
__global__ __launch_bounds__(256)
void tv_k(const u16* __restrict__ qkv, u16* __restrict__ vt) {
  __shared__ u16 t[64][65];
  int r0 = blockIdx.x * 64;       // global row tile (b*1024 + s0)
  int h = blockIdx.y;
  int b = r0 >> 10;
  int s0 = r0 & 1023;
#pragma unroll
  for (int i = 0; i < 16; ++i) {
    int idx = i * 256 + threadIdx.x;
    int r = idx >> 6, cc = idx & 63;
    t[r][cc] = qkv[(size_t)(r0 + r) * 3072 + 2048 + h * 64 + cc];
  }
  __syncthreads();
#pragma unroll
  for (int i = 0; i < 16; ++i) {
    int idx = i * 256 + threadIdx.x;
    int ch = idx >> 6, scc = idx & 63;
    vt[((size_t)(b * 16 + h) * 64 + ch) * 1024 + s0 + scc] = t[scc][ch];
  }
}

// ---------------- GEMM: C[M,N] = A[M,K](bf16) x Bt[N,K](bf16), fused epilogues ----------------
// EP 0: store bf16              (qkv)
// EP 1: bias + gelu -> bf16     (mlp1)
// EP 2: bias + resid + gate*val -> f32 (proj / mlp2)
__device__ __forceinline__ float gelu_f(float x) {
  float z = 1.5957691216057308f * (x + 0.044715f * x * x * x);
  return x / (1.f + __expf(-z));   // == 0.5x(1+tanh(sqrt(2/pi)(x+0.044715x^3)))
}

template <int EP>
__global__ __launch_bounds__(256)
void gemm_k(const u16* __restrict__ A, const u16* __restrict__ Bt,
            int N, int K,
            const float* __restrict__ bias, const float* __restrict__ resid,
            const float* __restrict__ gate, void* __restrict__ outp) {
  __shared__ __align__(16) u16 lds[2][2][128 * 32];
  const int bn = blockIdx.x, bm = blockIdx.y;
  const int tid = threadIdx.x;
  const int wave = tid >> 6, lane = tid & 63;
  const int l15 = lane & 15, lhi = lane >> 4;
  const int wr = wave >> 1, wc = wave & 1;
  f32x4 acc[4][4] = {};
  const int nkt = K >> 5;
  const size_t arow0 = (size_t)bm * 128;
  const size_t brow0 = (size_t)bn * 128;

  auto stage = [&](int buf, int kt) {
#pragma unroll
    for (int i = 0; i < 2; ++i) {
      int c = (i * 4 + wave) * 64 + lane;       // chunk id 0..511
      int row = c >> 2, kc = c & 3;             // 4x16B chunks per 32-elem row
      gload_lds16(A  + (arow0 + row) * K + (size_t)kt * 32 + kc * 8,
                  &lds[buf][0][(i * 4 + wave) * 512]);
      gload_lds16(Bt + (brow0 + row) * K + (size_t)kt * 32 + kc * 8,
                  &lds[buf][1][(i * 4 + wave) * 512]);
    }
  };

  stage(0, 0);
  __syncthreads();
  for (int kt = 0; kt < nkt; ++kt) {
    int cur = kt & 1;
    if (kt + 1 < nkt) stage(cur ^ 1, kt + 1);
    bf16x8 af[4], bfr[4];
#pragma unroll
    for (int m = 0; m < 4; ++m)
      af[m] = *(const bf16x8*)&lds[cur][0][(wr * 64 + m * 16 + l15) * 32 + lhi * 8];
#pragma unroll
    for (int n = 0; n < 4; ++n)
      bfr[n] = *(const bf16x8*)&lds[cur][1][(wc * 64 + n * 16 + l15) * 32 + lhi * 8];
#pragma unroll
    for (int m = 0; m < 4; ++m)
#pragma unroll
      for (int n = 0; n < 4; ++n)
        acc[m][n] = MFMA16(af[m], bfr[n], acc[m][n]);
    __syncthreads();
  }

#pragma unroll
  for (int m = 0; m < 4; ++m) {
    int row = bm * 128 + wr * 64 + m * 16 + lhi * 4;
#pragma unroll
    for (int n = 0; n < 4; ++n) {
      int col = bn * 128 + wc * 64 + n * 16 + l15;
#pragma unroll
      for (int r = 0; r < 4; ++r) {
        int rr = row + r;
        float v = acc[m][n][r];
        if (EP == 0) {
          ((u16*)outp)[(size_t)rr * N + col] = f2bf(v);
        } else if (EP == 1) {
          ((u16*)outp)[(size_t)rr * N + col] = f2bf(gelu_f(v + bias[col]));
        } else {
          float t = v + bias[col];
          int b = rr >> 10;
          float res = resid[(size_t)rr * N + col];
          ((float*)outp)[(size_t)rr * N + col] = res + gate[(size_t)b * 6144 + col] * t;
        }
      }
    }
  }
}

// ---------------- flash attention: block = (q-tile 64, head, batch) ----------------
__global__ __launch_bounds__(256)
void attn_k(const u16* __restrict__ qkv, const u16* __restrict__ vt,
            u16* __restrict__ y) {
  const int qt = blockIdx.x, h = blockIdx.y, b = blockIdx.z;
  const int tid = threadIdx.x, wave = tid >> 6, lane = tid & 63;
  const int l15 = lane & 15, lhi = lane >> 4;
  __shared__ __align__(16) u16 Qs[64 * 64];
  __shared__ __align__(16) u16 Ks[2][64 * 64];
  __shared__ __align__(16) u16 Vs[2][64 * 64];
  __shared__ __align__(16) u16 Ps[64 * 64];
  const size_t qrow0 = (size_t)b * 1024 + qt * 64;
  const size_t krow0 = (size_t)b * 1024;
  const size_t vrow0 = (size_t)(b * 16 + h) * 64;

  auto stageQ = [&]() {
#pragma unroll
    for (int i = 0; i < 2; ++i) {
      int c = (i * 4 + wave) * 64 + lane;
      int r = c >> 3, off = (c & 7) * 8;
      gload_lds16(qkv + (qrow0 + r) * 3072 + 1024 + h * 64 + off, &Qs[(i * 4 + wave) * 512]);
    }
  };
  auto stageKV = [&](int buf, int kt) {
#pragma unroll
    for (int i = 0; i < 2; ++i) {
      int c = (i * 4 + wave) * 64 + lane;
      int r = c >> 3, off = (c & 7) * 8;
      gload_lds16(qkv + (krow0 + kt * 64 + r) * 3072 + h * 64 + off, &Ks[buf][(i * 4 + wave) * 512]);
      gload_lds16(vt + (vrow0 + r) * 1024 + kt * 64 + off, &Vs[buf][(i * 4 + wave) * 512]);
    }
  };

  stageQ();
  stageKV(0, 0);
  __syncthreads();
  bf16x8 qf[2];
#pragma unroll
  for (int kk = 0; kk < 2; ++kk)
    qf[kk] = *(const bf16x8*)&Qs[(wave * 16 + l15) * 64 + kk * 32 + lhi * 8];

  float m_r[4], l_r[4];
  f32x4 o[4] = {};
#pragma unroll
  for (int r = 0; r < 4; ++r) { m_r[r] = -3.0e38f; l_r[r] = 0.f; }

  const float SCALE = 1.0f / 64.0f;   // faithful: q /= head_dim
  for (int kt = 0; kt < 16; ++kt) {
    int cur = kt & 1;
    if (kt < 15) stageKV(cur ^ 1, kt + 1);
    f32x4 sf[4] = {};
#pragma unroll
    for (int n = 0; n < 4; ++n) {
      bf16x8 k0 = *(const bf16x8*)&Ks[cur][(n * 16 + l15) * 64 + lhi * 8];
      bf16x8 k1 = *(const bf16x8*)&Ks[cur][(n * 16 + l15) * 64 + 32 + lhi * 8];
      sf[n] = MFMA16(qf[0], k0, sf[n]);
      sf[n] = MFMA16(qf[1], k1, sf[n]);
    }
#pragma unroll
    for (int r = 0; r < 4; ++r) {
      float mx = fmaxf(fmaxf(sf[0][r], sf[1][r]), fmaxf(sf[2][r], sf[3][r])) * SCALE;
      mx = fmaxf(mx, __shfl_xor(mx, 1));
      mx = fmaxf(mx, __shfl_xor(mx, 2));
      mx = fmaxf(mx, __shfl_xor(mx, 4));
      mx = fmaxf(mx, __shfl_xor(mx, 8));
      float mn = fmaxf(m_r[r], mx);
      float al = __expf(m_r[r] - mn);
      m_r[r] = mn;
      float p0 = __expf(sf[0][r] * SCALE - mn);
      float p1 = __expf(sf[1][r] * SCALE - mn);
      float p2 = __expf(sf[2][r] * SCALE - mn);
      float p3 = __expf(sf[3][r] * SCALE - mn);
      float rs = p0 + p1 + p2 + p3;
      rs += __shfl_xor(rs, 1);
      rs += __shfl_xor(rs, 2);
      rs += __shfl_xor(rs, 4);
      rs += __shfl_xor(rs, 8);
      l_r[r] = l_r[r] * al + rs;
      o[0][r] *= al; o[1][r] *= al; o[2][r] *= al; o[3][r] *= al;
      int prow = (wave * 16 + lhi * 4 + r) * 64 + l15;
      Ps[prow]      = f2bf(p0);
      Ps[prow + 16] = f2bf(p1);
      Ps[prow + 32] = f2bf(p2);
      Ps[prow + 48] = f2bf(p3);
    }
    __syncthreads();
    bf16x8 pf[2];
#pragma unroll
    for (int kk = 0; kk < 2; ++kk)
      pf[kk] = *(const bf16x8*)&Ps[(wave * 16 + l15) * 64 + kk * 32 + lhi * 8];
#pragma unroll
    for (int n = 0; n < 4; ++n) {
      bf16x8 v0 = *(const bf16x8*)&Vs[cur][(n * 16 + l15) * 64 + lhi * 8];
      bf16x8 v1 = *(const bf16x8*)&Vs[cur][(n * 16 + l15) * 64 + 32 + lhi * 8];
      o[n] = MFMA16(pf[0], v0, o[n]);
      o[n] = MFMA16(pf[1], v1, o[n]);
    }
    __syncthreads();
  }
#pragma unroll
  for (int r = 0; r < 4; ++r) {
    float inv = 1.0f / l_r[r];
    size_t yrow = (qrow0 + wave * 16 + lhi * 4 + r) * 1024 + h * 64 + l15;
    y[yrow]      = f2bf(o[0][r] * inv);
    y[yrow + 16] = f2bf(o[1][r] * inv);
    y[yrow + 32] = f2bf(o[2][r] * inv);
    y[yrow + 48] = f2bf(o[3][r] * inv);
  }
}

// ---------------- host ----------------
extern "C" void kernel_launch(void* const* d_in, const int* in_sizes, int n_in,
                              void* d_out, int out_size, void* d_ws, size_t ws_size,
                              hipStream_t stream) {
  const float* x      = (const float*)d_in[0];
  const float* c      = (const float*)d_in[1];
  const float* w_ada  = (const float*)d_in[2];
  const float* b_ada  = (const float*)d_in[3];
  const float* w_qkv  = (const float*)d_in[4];
  const float* w_proj = (const float*)d_in[5];
  const float* b_proj = (const float*)d_in[6];
  const float* w_mlp1 = (const float*)d_in[7];
  const float* b_mlp1 = (const float*)d_in[8];
  const float* w_mlp2 = (const float*)d_in[9];
  const float* b_mlp2 = (const float*)d_in[10];
  float* out = (float*)d_out;

  char* ws = (char*)d_ws;
  size_t off = 0;
  auto alloc = [&](size_t bytes) {
    void* p = ws + off;
    off += (bytes + 255) & ~(size_t)255;
    return p;
  };
  float* cmod  = (float*)alloc((size_t)8 * 6144 * 4);
  u16* wqkvT   = (u16*)alloc((size_t)3072 * 1024 * 2);
  u16* wprojT  = (u16*)alloc((size_t)1024 * 1024 * 2);
  u16* wmlp1T  = (u16*)alloc((size_t)4096 * 1024 * 2);
  u16* wmlp2T  = (u16*)alloc((size_t)1024 * 4096 * 2);
  u16* xmod    = (u16*)alloc((size_t)8192 * 1024 * 2);   // reused as attention out y
  u16* qkv     = (u16*)alloc((size_t)8192 * 3072 * 2);   // front reused as x_mod2
  u16* vt      = (u16*)alloc((size_t)8 * 16 * 64 * 1024 * 2);
  float* x1    = (float*)alloc((size_t)8192 * 1024 * 4);
  u16* hbuf    = (u16*)alloc((size_t)8192 * 4096 * 2);
  u16* ybuf  = xmod;   // x_mod dead after qkv GEMM
  u16* xmod2 = qkv;    // qkv dead after attention

  adaln_k<<<24, 256, 0, stream>>>(c, w_ada, b_ada, cmod);
  tcast_k<<<dim3(3072 / 64, 1024 / 64), 256, 0, stream>>>(w_qkv,  wqkvT,  1024, 3072);
  tcast_k<<<dim3(1024 / 64, 1024 / 64), 256, 0, stream>>>(w_proj, wprojT, 1024, 1024);
  tcast_k<<<dim3(4096 / 64, 1024 / 64), 256, 0, stream>>>(w_mlp1, wmlp1T, 1024, 4096);
  tcast_k<<<dim3(1024 / 64, 4096 / 64), 256, 0, stream>>>(w_mlp2, wmlp2T, 4096, 1024);
  lnmod_k<<<8192, 256, 0, stream>>>(x, cmod, 0, 1024, xmod);
  gemm_k<0><<<dim3(3072 / 128, 8192 / 128), 256, 0, stream>>>(
      xmod, wqkvT, 3072, 1024, nullptr, nullptr, nullptr, qkv);
  tv_k<<<dim3(128, 16), 256, 0, stream>>>(qkv, vt);
  attn_k<<<dim3(16, 16, 8), 256, 0, stream>>>(qkv, vt, ybuf);
  gemm_k<2><<<dim3(1024 / 128, 8192 / 128), 256, 0, stream>>>(
      ybuf, wprojT, 1024, 1024, b_proj, x, cmod + 2048, x1);
  lnmod_k<<<8192, 256, 0, stream>>>(x1, cmod, 3072, 4096, xmod2);
  gemm_k<1><<<dim3(4096 / 128, 8192 / 128), 256, 0, stream>>>(
      xmod2, wmlp1T, 4096, 1024, b_mlp1, nullptr, nullptr, hbuf);
  gemm_k<2><<<dim3(1024 / 128, 8192 / 128), 256, 0, stream>>>(
      hbuf, wmlp2T, 1024, 4096, b_mlp2, x1, cmod + 5120, out);
}

// Round 2
// 565.186 us; speedup vs baseline: 1.0917x; 1.0917x over previous
//
#include <hip/hip_runtime.h>
#include <stdint.h>

typedef unsigned short u16;
using bf16x8 = __attribute__((ext_vector_type(8))) __bf16;
using f32x4  = __attribute__((ext_vector_type(4))) float;

#define MFMA16(a,b,c) __builtin_amdgcn_mfma_f32_16x16x32_bf16((a),(b),(c),0,0,0)

__device__ __forceinline__ u16 f2bf(float f) {
  union { float f; uint32_t u; } v; v.f = f;
  uint32_t r = v.u + 0x7FFFu + ((v.u >> 16) & 1u);
  return (u16)(r >> 16);
}

// async global->LDS, 16B per lane; lds ptr must be wave-uniform (HW: base + lane*16)
__device__ __forceinline__ void gload_lds16(const void* g, void* l) {
  typedef const __attribute__((address_space(1))) void* gp_t;
  typedef __attribute__((address_space(3))) void* lp_t;
  __builtin_amdgcn_global_load_lds((gp_t)(uintptr_t)g,
                                   (lp_t)(uint32_t)(uintptr_t)l, 16, 0, 0);
}

// ---------------- adaLN: cmod = silu(c) @ w_ada + b_ada  [8,6144] ----------------
__global__ __launch_bounds__(256)
void adaln_k(const float* __restrict__ c, const float* __restrict__ w,
             const float* __restrict__ bias, float* __restrict__ cmod) {
  __shared__ float sil[8192];
  for (int i = threadIdx.x; i < 8192; i += 256) {
    float v = c[i];
    sil[i] = v / (1.f + __expf(-v));
  }
  __syncthreads();
  int j = blockIdx.x * 256 + threadIdx.x;  // < 6144
  float acc[8] = {0,0,0,0,0,0,0,0};
  for (int k = 0; k < 1024; ++k) {
    float wv = w[(size_t)k * 6144 + j];
#pragma unroll
    for (int b = 0; b < 8; ++b) acc[b] += sil[b * 1024 + k] * wv;
  }
  float bb = bias[j];
#pragma unroll
  for (int b = 0; b < 8; ++b) cmod[(size_t)b * 6144 + j] = acc[b] + bb;
}

// ------- weight cast+transpose: fp32 [K][N] -> bf16 [N][K]; cols [lo,hi) scaled -------
__global__ __launch_bounds__(256)
void tcast_k(const float* __restrict__ in, u16* __restrict__ out, int K, int N,
             int lo, int hi, float scale) {
  __shared__ u16 t[64][65];
  int n0 = blockIdx.x * 64, k0 = blockIdx.y * 64;
#pragma unroll
  for (int i = 0; i < 16; ++i) {
    int idx = i * 256 + threadIdx.x;
    int r = idx >> 6, cc = idx & 63;
    float v = in[(size_t)(k0 + r) * N + n0 + cc];
    int n = n0 + cc;
    if (n >= lo && n < hi) v *= scale;
    t[r][cc] = f2bf(v);
  }
  __syncthreads();
#pragma unroll
  for (int i = 0; i < 16; ++i) {
    int idx = i * 256 + threadIdx.x;
    int r = idx >> 6, cc = idx & 63;
    out[(size_t)(n0 + r) * K + k0 + cc] = t[cc][r];
  }
}

// ---------------- LN + modulate -> bf16 ----------------
__global__ __launch_bounds__(256)
void lnmod_k(const float* __restrict__ x, const float* __restrict__ cmod,
             int shift_off, int scale_off, u16* __restrict__ out) {
  int row = blockIdx.x;           // 0..8191
  int b = row >> 10;
  const float4* xr = (const float4*)(x + (size_t)row * 1024);
  float4 v = xr[threadIdx.x];
  float s = v.x + v.y + v.z + v.w;
  float sq = v.x * v.x + v.y * v.y + v.z * v.z + v.w * v.w;
#pragma unroll
  for (int m = 32; m >= 1; m >>= 1) {
    s  += __shfl_xor(s, m);
    sq += __shfl_xor(sq, m);
  }
  __shared__ float ss[4], ssq[4];
  int wave = threadIdx.x >> 6, lane = threadIdx.x & 63;
  if (lane == 0) { ss[wave] = s; ssq[wave] = sq; }
  __syncthreads();
  s  = ss[0] + ss[1] + ss[2] + ss[3];
  sq = ssq[0] + ssq[1] + ssq[2] + ssq[3];
  float mean = s * (1.f / 1024.f);
  float var  = sq * (1.f / 1024.f) - mean * mean;
  float rstd = rsqrtf(var + 1e-6f);
  int col = threadIdx.x * 4;
  const float* sh = cmod + (size_t)b * 6144 + shift_off + col;
  const float* sc = cmod + (size_t)b * 6144 + scale_off + col;
  float xv[4] = {v.x, v.y, v.z, v.w};
  union { u16 o[4]; uint64_t u; } pk;
#pragma unroll
  for (int j = 0; j < 4; ++j)
    pk.o[j] = f2bf((xv[j] - mean) * rstd * (1.f + sc[j]) + sh[j]);
  *(uint64_t*)(out + (size_t)row * 1024 + col) = pk.u;
}

// ---------------- transpose V section of qkv -> vt[b,h,ch,s] bf16 ----------------
__global__ __launch_bounds__(256)
void tv_k(const u16* __restrict__ qkv, u16* __restrict__ vt) {
  __shared__ u16 t[64][65];
  int r0 = blockIdx.x * 64;       // global row tile (b*1024 + s0)
  int h = blockIdx.y;
  int b = r0 >> 10;
  int s0 = r0 & 1023;
#pragma unroll
  for (int i = 0; i < 16; ++i) {
    int idx = i * 256 + threadIdx.x;
    int r = idx >> 6, cc = idx & 63;
    t[r][cc] = qkv[(size_t)(r0 + r) * 3072 + 2048 + h * 64 + cc];
  }
  __syncthreads();
#pragma unroll
  for (int i = 0; i < 16; ++i) {
    int idx = i * 256 + threadIdx.x;
    int ch = idx >> 6, scc = idx & 63;
    vt[((size_t)(b * 16 + h) * 64 + ch) * 1024 + s0 + scc] = t[scc][ch];
  }
}

// ---------------- GEMM: C[M,N] = A[M,K](bf16) x Bt[N,K](bf16), fused epilogues ----------------
__device__ __forceinline__ float gelu_f(float x) {
  float z = 1.5957691216057308f * (x + 0.044715f * x * x * x);
  return x / (1.f + __expf(-z));
}

template <int EP>
__global__ __launch_bounds__(256)
void gemm_k(const u16* __restrict__ A, const u16* __restrict__ Bt,
            int N, int K,
            const float* __restrict__ bias, const float* __restrict__ resid,
            const float* __restrict__ gate, void* __restrict__ outp) {
  __shared__ __align__(16) u16 lds[2][2][128 * 32];
  const int bn = blockIdx.x, bm = blockIdx.y;
  const int tid = threadIdx.x;
  const int wave = tid >> 6, lane = tid & 63;
  const int l15 = lane & 15, lhi = lane >> 4;
  const int wr = wave >> 1, wc = wave & 1;
  f32x4 acc[4][4] = {};
  const int nkt = K >> 5;
  const size_t arow0 = (size_t)bm * 128;
  const size_t brow0 = (size_t)bn * 128;

  auto stage = [&](int buf, int kt) {
#pragma unroll
    for (int i = 0; i < 2; ++i) {
      int c = (i * 4 + wave) * 64 + lane;       // chunk id 0..511
      int row = c >> 2, kc = c & 3;             // 4x16B chunks per 32-elem row
      gload_lds16(A  + (arow0 + row) * K + (size_t)kt * 32 + kc * 8,
                  &lds[buf][0][(i * 4 + wave) * 512]);
      gload_lds16(Bt + (brow0 + row) * K + (size_t)kt * 32 + kc * 8,
                  &lds[buf][1][(i * 4 + wave) * 512]);
    }
  };

  stage(0, 0);
  __syncthreads();
  for (int kt = 0; kt < nkt; ++kt) {
    int cur = kt & 1;
    if (kt + 1 < nkt) stage(cur ^ 1, kt + 1);
    bf16x8 af[4], bfr[4];
#pragma unroll
    for (int m = 0; m < 4; ++m)
      af[m] = *(const bf16x8*)&lds[cur][0][(wr * 64 + m * 16 + l15) * 32 + lhi * 8];
#pragma unroll
    for (int n = 0; n < 4; ++n)
      bfr[n] = *(const bf16x8*)&lds[cur][1][(wc * 64 + n * 16 + l15) * 32 + lhi * 8];
#pragma unroll
    for (int m = 0; m < 4; ++m)
#pragma unroll
      for (int n = 0; n < 4; ++n)
        acc[m][n] = MFMA16(af[m], bfr[n], acc[m][n]);
    __syncthreads();
  }

#pragma unroll
  for (int m = 0; m < 4; ++m) {
    int row = bm * 128 + wr * 64 + m * 16 + lhi * 4;
#pragma unroll
    for (int n = 0; n < 4; ++n) {
      int col = bn * 128 + wc * 64 + n * 16 + l15;
#pragma unroll
      for (int r = 0; r < 4; ++r) {
        int rr = row + r;
        float v = acc[m][n][r];
        if (EP == 0) {
          ((u16*)outp)[(size_t)rr * N + col] = f2bf(v);
        } else if (EP == 1) {
          ((u16*)outp)[(size_t)rr * N + col] = f2bf(gelu_f(v + bias[col]));
        } else {
          float t = v + bias[col];
          int b = rr >> 10;
          float res = resid[(size_t)rr * N + col];
          ((float*)outp)[(size_t)rr * N + col] = res + gate[(size_t)b * 6144 + col] * t;
        }
      }
    }
  }
}

// ---------------- flash attention: block = (q-tile 64, head, batch) ----------------
// LDS tiles are 64 rows x 64 bf16 (128B rows): XOR-swizzled by (row&7) at 16B-chunk
// granularity. global_load_lds writes linearly -> inverse swizzle on SOURCE address,
// swizzle on every read (rule: both-sides-or-neither).
__global__ __launch_bounds__(256)
void attn_k(const u16* __restrict__ qkv, const u16* __restrict__ vt,
            u16* __restrict__ y) {
  const int qt = blockIdx.x, h = blockIdx.y, b = blockIdx.z;
  const int tid = threadIdx.x, wave = tid >> 6, lane = tid & 63;
  const int l15 = lane & 15, lhi = lane >> 4;
  __shared__ __align__(16) u16 Qs[64 * 64];
  __shared__ __align__(16) u16 Ks[2][64 * 64];
  __shared__ __align__(16) u16 Vs[2][64 * 64];
  __shared__ __align__(16) u16 Ps[64 * 64];
  const size_t qrow0 = (size_t)b * 1024 + qt * 64;
  const size_t krow0 = (size_t)b * 1024;
  const size_t vrow0 = (size_t)(b * 16 + h) * 64;

  auto stageQ = [&]() {
#pragma unroll
    for (int i = 0; i < 2; ++i) {
      int c = (i * 4 + wave) * 64 + lane;
      int r = c >> 3, j = (c & 7) ^ (c >> 3 & 7);
      gload_lds16(qkv + (qrow0 + r) * 3072 + 1024 + h * 64 + j * 8,
                  &Qs[(i * 4 + wave) * 512]);
    }
  };
  auto stageKV = [&](int buf, int kt) {
#pragma unroll
    for (int i = 0; i < 2; ++i) {
      int c = (i * 4 + wave) * 64 + lane;
      int r = c >> 3, j = (c & 7) ^ (c >> 3 & 7);
      gload_lds16(qkv + (krow0 + kt * 64 + r) * 3072 + h * 64 + j * 8,
                  &Ks[buf][(i * 4 + wave) * 512]);
      gload_lds16(vt + (vrow0 + r) * 1024 + kt * 64 + j * 8,
                  &Vs[buf][(i * 4 + wave) * 512]);
    }
  };
  // swizzled 16B fragment read: logical (row, chunk cc in 0..7)
  auto ldb = [](const u16* base, int row, int cc) -> bf16x8 {
    return *(const bf16x8*)&base[row * 64 + ((cc ^ (row & 7)) << 3)];
  };

  stageQ();
  stageKV(0, 0);
  __syncthreads();
  bf16x8 qf[2];
  qf[0] = ldb(Qs, wave * 16 + l15, lhi);
  qf[1] = ldb(Qs, wave * 16 + l15, 4 + lhi);

  bf16x8 ones;
#pragma unroll
  for (int j = 0; j < 8; ++j) ones[j] = (__bf16)1.0f;

  float m_r[4];
  f32x4 o[5] = {};   // o[4] accumulates the softmax denominator (ones-column MFMA)
#pragma unroll
  for (int r = 0; r < 4; ++r) m_r[r] = -3.0e38f;

  for (int kt = 0; kt < 16; ++kt) {
    int cur = kt & 1;
    if (kt < 15) stageKV(cur ^ 1, kt + 1);
    f32x4 sf[4] = {};
    __builtin_amdgcn_s_setprio(1);
#pragma unroll
    for (int n = 0; n < 4; ++n) {
      bf16x8 k0 = ldb(Ks[cur], n * 16 + l15, lhi);
      bf16x8 k1 = ldb(Ks[cur], n * 16 + l15, 4 + lhi);
      sf[n] = MFMA16(qf[0], k0, sf[n]);
      sf[n] = MFMA16(qf[1], k1, sf[n]);
    }
    __builtin_amdgcn_s_setprio(0);
    // online softmax (scores pre-scaled: q-weights carry 1/64)
#pragma unroll
    for (int r = 0; r < 4; ++r) {
      float mx = fmaxf(fmaxf(sf[0][r], sf[1][r]), fmaxf(sf[2][r], sf[3][r]));
      mx = fmaxf(mx, __shfl_xor(mx, 1));
      mx = fmaxf(mx, __shfl_xor(mx, 2));
      mx = fmaxf(mx, __shfl_xor(mx, 4));
      mx = fmaxf(mx, __shfl_xor(mx, 8));
      float mn = fmaxf(m_r[r], mx);
      float al = __expf(m_r[r] - mn);
      m_r[r] = mn;
      float p0 = __expf(sf[0][r] - mn);
      float p1 = __expf(sf[1][r] - mn);
      float p2 = __expf(sf[2][r] - mn);
      float p3 = __expf(sf[3][r] - mn);
      o[0][r] *= al; o[1][r] *= al; o[2][r] *= al; o[3][r] *= al; o[4][r] *= al;
      int row = wave * 16 + lhi * 4 + r;
      int rb = row * 64, sw = (row & 7) << 3;
      Ps[rb + (l15 ^ sw)]        = f2bf(p0);
      Ps[rb + ((l15 + 16) ^ sw)] = f2bf(p1);
      Ps[rb + ((l15 + 32) ^ sw)] = f2bf(p2);
      Ps[rb + ((l15 + 48) ^ sw)] = f2bf(p3);
    }
    // P is wave-private (each wave writes and reads only its own 16 rows):
    // no barrier needed before the PV reads, only in-wave lgkmcnt (compiler).
    bf16x8 pf0 = ldb(Ps, wave * 16 + l15, lhi);
    bf16x8 pf1 = ldb(Ps, wave * 16 + l15, 4 + lhi);
    __builtin_amdgcn_s_setprio(1);
#pragma unroll
    for (int n = 0; n < 4; ++n) {
      bf16x8 v0 = ldb(Vs[cur], n * 16 + l15, lhi);
      bf16x8 v1 = ldb(Vs[cur], n * 16 + l15, 4 + lhi);
      o[n] = MFMA16(pf0, v0, o[n]);
      o[n] = MFMA16(pf1, v1, o[n]);
    }
    o[4] = MFMA16(pf0, ones, o[4]);
    o[4] = MFMA16(pf1, ones, o[4]);
    __builtin_amdgcn_s_setprio(0);
    __syncthreads();   // single barrier per tile: guards K/V double-buffer swap
  }
#pragma unroll
  for (int r = 0; r < 4; ++r) {
    float inv = 1.0f / o[4][r];
    size_t yrow = (qrow0 + wave * 16 + lhi * 4 + r) * 1024 + h * 64 + l15;
    y[yrow]      = f2bf(o[0][r] * inv);
    y[yrow + 16] = f2bf(o[1][r] * inv);
    y[yrow + 32] = f2bf(o[2][r] * inv);
    y[yrow + 48] = f2bf(o[3][r] * inv);
  }
}

// ---------------- host ----------------
extern "C" void kernel_launch(void* const* d_in, const int* in_sizes, int n_in,
                              void* d_out, int out_size, void* d_ws, size_t ws_size,
                              hipStream_t stream) {
  const float* x      = (const float*)d_in[0];
  const float* c      = (const float*)d_in[1];
  const float* w_ada  = (const float*)d_in[2];
  const float* b_ada  = (const float*)d_in[3];
  const float* w_qkv  = (const float*)d_in[4];
  const float* w_proj = (const float*)d_in[5];
  const float* b_proj = (const float*)d_in[6];
  const float* w_mlp1 = (const float*)d_in[7];
  const float* b_mlp1 = (const float*)d_in[8];
  const float* w_mlp2 = (const float*)d_in[9];
  const float* b_mlp2 = (const float*)d_in[10];
  float* out = (float*)d_out;

  char* ws = (char*)d_ws;
  size_t off = 0;
  auto alloc = [&](size_t bytes) {
    void* p = ws + off;
    off += (bytes + 255) & ~(size_t)255;
    return p;
  };
  float* cmod  = (float*)alloc((size_t)8 * 6144 * 4);
  u16* wqkvT   = (u16*)alloc((size_t)3072 * 1024 * 2);
  u16* wprojT  = (u16*)alloc((size_t)1024 * 1024 * 2);
  u16* wmlp1T  = (u16*)alloc((size_t)4096 * 1024 * 2);
  u16* wmlp2T  = (u16*)alloc((size_t)1024 * 4096 * 2);
  u16* xmod    = (u16*)alloc((size_t)8192 * 1024 * 2);   // reused as attention out y
  u16* qkv     = (u16*)alloc((size_t)8192 * 3072 * 2);   // front reused as x_mod2
  u16* vt      = (u16*)alloc((size_t)8 * 16 * 64 * 1024 * 2);
  float* x1    = (float*)alloc((size_t)8192 * 1024 * 4);
  u16* hbuf    = (u16*)alloc((size_t)8192 * 4096 * 2);
  u16* ybuf  = xmod;   // x_mod dead after qkv GEMM
  u16* xmod2 = qkv;    // qkv dead after attention

  adaln_k<<<24, 256, 0, stream>>>(c, w_ada, b_ada, cmod);
  // q section (output cols 1024..2047) carries the 1/64 score scale (exact in bf16)
  tcast_k<<<dim3(3072 / 64, 1024 / 64), 256, 0, stream>>>(w_qkv,  wqkvT,  1024, 3072,
                                                          1024, 2048, 1.0f / 64.0f);
  tcast_k<<<dim3(1024 / 64, 1024 / 64), 256, 0, stream>>>(w_proj, wprojT, 1024, 1024, 0, 0, 1.f);
  tcast_k<<<dim3(4096 / 64, 1024 / 64), 256, 0, stream>>>(w_mlp1, wmlp1T, 1024, 4096, 0, 0, 1.f);
  tcast_k<<<dim3(1024 / 64, 4096 / 64), 256, 0, stream>>>(w_mlp2, wmlp2T, 4096, 1024, 0, 0, 1.f);
  lnmod_k<<<8192, 256, 0, stream>>>(x, cmod, 0, 1024, xmod);
  gemm_k<0><<<dim3(3072 / 128, 8192 / 128), 256, 0, stream>>>(
      xmod, wqkvT, 3072, 1024, nullptr, nullptr, nullptr, qkv);
  tv_k<<<dim3(128, 16), 256, 0, stream>>>(qkv, vt);
  attn_k<<<dim3(16, 16, 8), 256, 0, stream>>>(qkv, vt, ybuf);
  gemm_k<2><<<dim3(1024 / 128, 8192 / 128), 256, 0, stream>>>(
      ybuf, wprojT, 1024, 1024, b_proj, x, cmod + 2048, x1);
  lnmod_k<<<8192, 256, 0, stream>>>(x1, cmod, 3072, 4096, xmod2);
  gemm_k<1><<<dim3(4096 / 128, 8192 / 128), 256, 0, stream>>>(
      xmod2, wmlp1T, 4096, 1024, b_mlp1, nullptr, nullptr, hbuf);
  gemm_k<2><<<dim3(1024 / 128, 8192 / 128), 256, 0, stream>>>(
      hbuf, wmlp2T, 1024, 4096, b_mlp2, x1, cmod + 5120, out);
}

// Round 3
// 434.932 us; speedup vs baseline: 1.4187x; 1.2995x over previous
//
#include <hip/hip_runtime.h>
#include <stdint.h>

typedef unsigned short u16;
using bf16x8 = __attribute__((ext_vector_type(8))) __bf16;
using f32x4  = __attribute__((ext_vector_type(4))) float;

#define MFMA16(a,b,c) __builtin_amdgcn_mfma_f32_16x16x32_bf16((a),(b),(c),0,0,0)

__device__ __forceinline__ u16 f2bf(float f) {
  union { float f; uint32_t u; } v; v.f = f;
  uint32_t r = v.u + 0x7FFFu + ((v.u >> 16) & 1u);
  return (u16)(r >> 16);
}

// async global->LDS, 16B per lane; lds ptr must be wave-uniform (HW: base + lane*16)
__device__ __forceinline__ void gload_lds16(const void* g, void* l) {
  typedef const __attribute__((address_space(1))) void* gp_t;
  typedef __attribute__((address_space(3))) void* lp_t;
  __builtin_amdgcn_global_load_lds((gp_t)(uintptr_t)g,
                                   (lp_t)(uint32_t)(uintptr_t)l, 16, 0, 0);
}

// ---------------- adaLN stage 1: partial[ks][b][j] = sum_{k in slice} silu(c)[b,k] w[k,j] ----------
// grid: (jb 0..23, ks 0..31); each w element read exactly once.
__global__ __launch_bounds__(256)
void adaln_part_k(const float* __restrict__ c, const float* __restrict__ w,
                  float* __restrict__ partial) {
  const int jb = blockIdx.x, ks = blockIdx.y;
  const int j = jb * 256 + threadIdx.x;
  __shared__ float sil[8][32];
  {
    int b = threadIdx.x >> 5, kk = threadIdx.x & 31;
    float v = c[b * 1024 + ks * 32 + kk];
    sil[b][kk] = v / (1.f + __expf(-v));
  }
  __syncthreads();
  float acc[8] = {0,0,0,0,0,0,0,0};
#pragma unroll 8
  for (int kk = 0; kk < 32; ++kk) {
    float wv = w[(size_t)(ks * 32 + kk) * 6144 + j];
#pragma unroll
    for (int b = 0; b < 8; ++b) acc[b] += sil[b][kk] * wv;
  }
#pragma unroll
  for (int b = 0; b < 8; ++b)
    partial[((size_t)ks * 8 + b) * 6144 + j] = acc[b];
}

// ---------------- adaLN stage 2: cmod[b][j] = bias[j] + sum_ks partial[ks][b][j] ----------------
__global__ __launch_bounds__(256)
void adaln_red_k(const float* __restrict__ partial, const float* __restrict__ bias,
                 float* __restrict__ cmod) {
  int g = blockIdx.x * 256 + threadIdx.x;    // 0 .. 8*6144-1
  int j = g % 6144;
  float s = bias[j];
#pragma unroll 8
  for (int ks = 0; ks < 32; ++ks)
    s += partial[(size_t)ks * 8 * 6144 + g];
  cmod[g] = s;
}

// ------- weight cast+transpose: fp32 [K][N] -> bf16 [N][K]; cols [lo,hi) scaled -------
__global__ __launch_bounds__(256)
void tcast_k(const float* __restrict__ in, u16* __restrict__ out, int K, int N,
             int lo, int hi, float scale) {
  __shared__ u16 t[64][65];
  int n0 = blockIdx.x * 64, k0 = blockIdx.y * 64;
#pragma unroll
  for (int i = 0; i < 16; ++i) {
    int idx = i * 256 + threadIdx.x;
    int r = idx >> 6, cc = idx & 63;
    float v = in[(size_t)(k0 + r) * N + n0 + cc];
    int n = n0 + cc;
    if (n >= lo && n < hi) v *= scale;
    t[r][cc] = f2bf(v);
  }
  __syncthreads();
#pragma unroll
  for (int i = 0; i < 16; ++i) {
    int idx = i * 256 + threadIdx.x;
    int r = idx >> 6, cc = idx & 63;
    out[(size_t)(n0 + r) * K + k0 + cc] = t[cc][r];
  }
}

// ---------------- LN + modulate -> bf16 ----------------
__global__ __launch_bounds__(256)
void lnmod_k(const float* __restrict__ x, const float* __restrict__ cmod,
             int shift_off, int scale_off, u16* __restrict__ out) {
  int row = blockIdx.x;           // 0..8191
  int b = row >> 10;
  const float4* xr = (const float4*)(x + (size_t)row * 1024);
  float4 v = xr[threadIdx.x];
  float s = v.x + v.y + v.z + v.w;
  float sq = v.x * v.x + v.y * v.y + v.z * v.z + v.w * v.w;
#pragma unroll
  for (int m = 32; m >= 1; m >>= 1) {
    s  += __shfl_xor(s, m);
    sq += __shfl_xor(sq, m);
  }
  __shared__ float ss[4], ssq[4];
  int wave = threadIdx.x >> 6, lane = threadIdx.x & 63;
  if (lane == 0) { ss[wave] = s; ssq[wave] = sq; }
  __syncthreads();
  s  = ss[0] + ss[1] + ss[2] + ss[3];
  sq = ssq[0] + ssq[1] + ssq[2] + ssq[3];
  float mean = s * (1.f / 1024.f);
  float var  = sq * (1.f / 1024.f) - mean * mean;
  float rstd = rsqrtf(var + 1e-6f);
  int col = threadIdx.x * 4;
  const float* sh = cmod + (size_t)b * 6144 + shift_off + col;
  const float* sc = cmod + (size_t)b * 6144 + scale_off + col;
  float xv[4] = {v.x, v.y, v.z, v.w};
  union { u16 o[4]; uint64_t u; } pk;
#pragma unroll
  for (int j = 0; j < 4; ++j)
    pk.o[j] = f2bf((xv[j] - mean) * rstd * (1.f + sc[j]) + sh[j]);
  *(uint64_t*)(out + (size_t)row * 1024 + col) = pk.u;
}

// ---------------- transpose V section of qkv -> vt[b,h,ch,s] bf16 ----------------
__global__ __launch_bounds__(256)
void tv_k(const u16* __restrict__ qkv, u16* __restrict__ vt) {
  __shared__ u16 t[64][65];
  int r0 = blockIdx.x * 64;       // global row tile (b*1024 + s0)
  int h = blockIdx.y;
  int b = r0 >> 10;
  int s0 = r0 & 1023;
#pragma unroll
  for (int i = 0; i < 16; ++i) {
    int idx = i * 256 + threadIdx.x;
    int r = idx >> 6, cc = idx & 63;
    t[r][cc] = qkv[(size_t)(r0 + r) * 3072 + 2048 + h * 64 + cc];
  }
  __syncthreads();
#pragma unroll
  for (int i = 0; i < 16; ++i) {
    int idx = i * 256 + threadIdx.x;
    int ch = idx >> 6, scc = idx & 63;
    vt[((size_t)(b * 16 + h) * 64 + ch) * 1024 + s0 + scc] = t[scc][ch];
  }
}

// ---------------- GEMM: C[M,N] = A[M,K](bf16) x Bt[N,K](bf16), fused epilogues ----------------
__device__ __forceinline__ float gelu_f(float x) {
  float z = 1.5957691216057308f * (x + 0.044715f * x * x * x);
  return x / (1.f + __expf(-z));
}

template <int EP>
__global__ __launch_bounds__(256)
void gemm_k(const u16* __restrict__ A, const u16* __restrict__ Bt,
            int N, int K,
            const float* __restrict__ bias, const float* __restrict__ resid,
            const float* __restrict__ gate, void* __restrict__ outp) {
  __shared__ __align__(16) u16 lds[2][2][128 * 32];
  const int bn = blockIdx.x, bm = blockIdx.y;
  const int tid = threadIdx.x;
  const int wave = tid >> 6, lane = tid & 63;
  const int l15 = lane & 15, lhi = lane >> 4;
  const int wr = wave >> 1, wc = wave & 1;
  f32x4 acc[4][4] = {};
  const int nkt = K >> 5;
  const size_t arow0 = (size_t)bm * 128;
  const size_t brow0 = (size_t)bn * 128;

  auto stage = [&](int buf, int kt) {
#pragma unroll
    for (int i = 0; i < 2; ++i) {
      int c = (i * 4 + wave) * 64 + lane;       // chunk id 0..511
      int row = c >> 2, kc = c & 3;             // 4x16B chunks per 32-elem row
      gload_lds16(A  + (arow0 + row) * K + (size_t)kt * 32 + kc * 8,
                  &lds[buf][0][(i * 4 + wave) * 512]);
      gload_lds16(Bt + (brow0 + row) * K + (size_t)kt * 32 + kc * 8,
                  &lds[buf][1][(i * 4 + wave) * 512]);
    }
  };

  stage(0, 0);
  __syncthreads();
  for (int kt = 0; kt < nkt; ++kt) {
    int cur = kt & 1;
    if (kt + 1 < nkt) stage(cur ^ 1, kt + 1);
    bf16x8 af[4], bfr[4];
#pragma unroll
    for (int m = 0; m < 4; ++m)
      af[m] = *(const bf16x8*)&lds[cur][0][(wr * 64 + m * 16 + l15) * 32 + lhi * 8];
#pragma unroll
    for (int n = 0; n < 4; ++n)
      bfr[n] = *(const bf16x8*)&lds[cur][1][(wc * 64 + n * 16 + l15) * 32 + lhi * 8];
#pragma unroll
    for (int m = 0; m < 4; ++m)
#pragma unroll
      for (int n = 0; n < 4; ++n)
        acc[m][n] = MFMA16(af[m], bfr[n], acc[m][n]);
    __syncthreads();
  }

#pragma unroll
  for (int m = 0; m < 4; ++m) {
    int row = bm * 128 + wr * 64 + m * 16 + lhi * 4;
#pragma unroll
    for (int n = 0; n < 4; ++n) {
      int col = bn * 128 + wc * 64 + n * 16 + l15;
#pragma unroll
      for (int r = 0; r < 4; ++r) {
        int rr = row + r;
        float v = acc[m][n][r];
        if (EP == 0) {
          ((u16*)outp)[(size_t)rr * N + col] = f2bf(v);
        } else if (EP == 1) {
          ((u16*)outp)[(size_t)rr * N + col] = f2bf(gelu_f(v + bias[col]));
        } else {
          float t = v + bias[col];
          int b = rr >> 10;
          float res = resid[(size_t)rr * N + col];
          ((float*)outp)[(size_t)rr * N + col] = res + gate[(size_t)b * 6144 + col] * t;
        }
      }
    }
  }
}

// ---------------- flash attention: block = (q-tile 64, head, batch) ----------------
// LDS tiles are 64 rows x 64 bf16 (128B rows): XOR-swizzled by (row&7) at 16B-chunk
// granularity. global_load_lds writes linearly -> inverse swizzle on SOURCE address,
// swizzle on every read (rule: both-sides-or-neither).
__global__ __launch_bounds__(256)
void attn_k(const u16* __restrict__ qkv, const u16* __restrict__ vt,
            u16* __restrict__ y) {
  const int qt = blockIdx.x, h = blockIdx.y, b = blockIdx.z;
  const int tid = threadIdx.x, wave = tid >> 6, lane = tid & 63;
  const int l15 = lane & 15, lhi = lane >> 4;
  __shared__ __align__(16) u16 Qs[64 * 64];
  __shared__ __align__(16) u16 Ks[2][64 * 64];
  __shared__ __align__(16) u16 Vs[2][64 * 64];
  __shared__ __align__(16) u16 Ps[64 * 64];
  const size_t qrow0 = (size_t)b * 1024 + qt * 64;
  const size_t krow0 = (size_t)b * 1024;
  const size_t vrow0 = (size_t)(b * 16 + h) * 64;

  auto stageQ = [&]() {
#pragma unroll
    for (int i = 0; i < 2; ++i) {
      int c = (i * 4 + wave) * 64 + lane;
      int r = c >> 3, j = (c & 7) ^ (c >> 3 & 7);
      gload_lds16(qkv + (qrow0 + r) * 3072 + 1024 + h * 64 + j * 8,
                  &Qs[(i * 4 + wave) * 512]);
    }
  };
  auto stageKV = [&](int buf, int kt) {
#pragma unroll
    for (int i = 0; i < 2; ++i) {
      int c = (i * 4 + wave) * 64 + lane;
      int r = c >> 3, j = (c & 7) ^ (c >> 3 & 7);
      gload_lds16(qkv + (krow0 + kt * 64 + r) * 3072 + h * 64 + j * 8,
                  &Ks[buf][(i * 4 + wave) * 512]);
      gload_lds16(vt + (vrow0 + r) * 1024 + kt * 64 + j * 8,
                  &Vs[buf][(i * 4 + wave) * 512]);
    }
  };
  // swizzled 16B fragment read: logical (row, chunk cc in 0..7)
  auto ldb = [](const u16* base, int row, int cc) -> bf16x8 {
    return *(const bf16x8*)&base[row * 64 + ((cc ^ (row & 7)) << 3)];
  };

  stageQ();
  stageKV(0, 0);
  __syncthreads();
  bf16x8 qf[2];
  qf[0] = ldb(Qs, wave * 16 + l15, lhi);
  qf[1] = ldb(Qs, wave * 16 + l15, 4 + lhi);

  bf16x8 ones;
#pragma unroll
  for (int j = 0; j < 8; ++j) ones[j] = (__bf16)1.0f;

  float m_r[4];
  f32x4 o[5] = {};   // o[4] accumulates the softmax denominator (ones-column MFMA)
#pragma unroll
  for (int r = 0; r < 4; ++r) m_r[r] = -3.0e38f;

  for (int kt = 0; kt < 16; ++kt) {
    int cur = kt & 1;
    if (kt < 15) stageKV(cur ^ 1, kt + 1);
    f32x4 sf[4] = {};
    __builtin_amdgcn_s_setprio(1);
#pragma unroll
    for (int n = 0; n < 4; ++n) {
      bf16x8 k0 = ldb(Ks[cur], n * 16 + l15, lhi);
      bf16x8 k1 = ldb(Ks[cur], n * 16 + l15, 4 + lhi);
      sf[n] = MFMA16(qf[0], k0, sf[n]);
      sf[n] = MFMA16(qf[1], k1, sf[n]);
    }
    __builtin_amdgcn_s_setprio(0);
    // online softmax (scores pre-scaled: q-weights carry 1/64)
#pragma unroll
    for (int r = 0; r < 4; ++r) {
      float mx = fmaxf(fmaxf(sf[0][r], sf[1][r]), fmaxf(sf[2][r], sf[3][r]));
      mx = fmaxf(mx, __shfl_xor(mx, 1));
      mx = fmaxf(mx, __shfl_xor(mx, 2));
      mx = fmaxf(mx, __shfl_xor(mx, 4));
      mx = fmaxf(mx, __shfl_xor(mx, 8));
      float mn = fmaxf(m_r[r], mx);
      float al = __expf(m_r[r] - mn);
      m_r[r] = mn;
      float p0 = __expf(sf[0][r] - mn);
      float p1 = __expf(sf[1][r] - mn);
      float p2 = __expf(sf[2][r] - mn);
      float p3 = __expf(sf[3][r] - mn);
      o[0][r] *= al; o[1][r] *= al; o[2][r] *= al; o[3][r] *= al; o[4][r] *= al;
      int row = wave * 16 + lhi * 4 + r;
      int rb = row * 64, sw = (row & 7) << 3;
      Ps[rb + (l15 ^ sw)]        = f2bf(p0);
      Ps[rb + ((l15 + 16) ^ sw)] = f2bf(p1);
      Ps[rb + ((l15 + 32) ^ sw)] = f2bf(p2);
      Ps[rb + ((l15 + 48) ^ sw)] = f2bf(p3);
    }
    // P is wave-private (each wave writes and reads only its own 16 rows):
    // no barrier needed before the PV reads, only in-wave lgkmcnt (compiler).
    bf16x8 pf0 = ldb(Ps, wave * 16 + l15, lhi);
    bf16x8 pf1 = ldb(Ps, wave * 16 + l15, 4 + lhi);
    __builtin_amdgcn_s_setprio(1);
#pragma unroll
    for (int n = 0; n < 4; ++n) {
      bf16x8 v0 = ldb(Vs[cur], n * 16 + l15, lhi);
      bf16x8 v1 = ldb(Vs[cur], n * 16 + l15, 4 + lhi);
      o[n] = MFMA16(pf0, v0, o[n]);
      o[n] = MFMA16(pf1, v1, o[n]);
    }
    o[4] = MFMA16(pf0, ones, o[4]);
    o[4] = MFMA16(pf1, ones, o[4]);
    __builtin_amdgcn_s_setprio(0);
    __syncthreads();   // single barrier per tile: guards K/V double-buffer swap
  }
#pragma unroll
  for (int r = 0; r < 4; ++r) {
    float inv = 1.0f / o[4][r];
    size_t yrow = (qrow0 + wave * 16 + lhi * 4 + r) * 1024 + h * 64 + l15;
    y[yrow]      = f2bf(o[0][r] * inv);
    y[yrow + 16] = f2bf(o[1][r] * inv);
    y[yrow + 32] = f2bf(o[2][r] * inv);
    y[yrow + 48] = f2bf(o[3][r] * inv);
  }
}

// ---------------- host ----------------
extern "C" void kernel_launch(void* const* d_in, const int* in_sizes, int n_in,
                              void* d_out, int out_size, void* d_ws, size_t ws_size,
                              hipStream_t stream) {
  const float* x      = (const float*)d_in[0];
  const float* c      = (const float*)d_in[1];
  const float* w_ada  = (const float*)d_in[2];
  const float* b_ada  = (const float*)d_in[3];
  const float* w_qkv  = (const float*)d_in[4];
  const float* w_proj = (const float*)d_in[5];
  const float* b_proj = (const float*)d_in[6];
  const float* w_mlp1 = (const float*)d_in[7];
  const float* b_mlp1 = (const float*)d_in[8];
  const float* w_mlp2 = (const float*)d_in[9];
  const float* b_mlp2 = (const float*)d_in[10];
  float* out = (float*)d_out;

  char* ws = (char*)d_ws;
  size_t off = 0;
  auto alloc = [&](size_t bytes) {
    void* p = ws + off;
    off += (bytes + 255) & ~(size_t)255;
    return p;
  };
  float* cmod  = (float*)alloc((size_t)8 * 6144 * 4);
  float* apart = (float*)alloc((size_t)32 * 8 * 6144 * 4);
  u16* wqkvT   = (u16*)alloc((size_t)3072 * 1024 * 2);
  u16* wprojT  = (u16*)alloc((size_t)1024 * 1024 * 2);
  u16* wmlp1T  = (u16*)alloc((size_t)4096 * 1024 * 2);
  u16* wmlp2T  = (u16*)alloc((size_t)1024 * 4096 * 2);
  u16* xmod    = (u16*)alloc((size_t)8192 * 1024 * 2);   // reused as attention out y
  u16* qkv     = (u16*)alloc((size_t)8192 * 3072 * 2);   // front reused as x_mod2
  u16* vt      = (u16*)alloc((size_t)8 * 16 * 64 * 1024 * 2);
  float* x1    = (float*)alloc((size_t)8192 * 1024 * 4);
  u16* hbuf    = (u16*)alloc((size_t)8192 * 4096 * 2);
  u16* ybuf  = xmod;   // x_mod dead after qkv GEMM
  u16* xmod2 = qkv;    // qkv dead after attention

  adaln_part_k<<<dim3(24, 32), 256, 0, stream>>>(c, w_ada, apart);
  adaln_red_k<<<192, 256, 0, stream>>>(apart, b_ada, cmod);
  // q section (output cols 1024..2047) carries the 1/64 score scale (exact in bf16)
  tcast_k<<<dim3(3072 / 64, 1024 / 64), 256, 0, stream>>>(w_qkv,  wqkvT,  1024, 3072,
                                                          1024, 2048, 1.0f / 64.0f);
  tcast_k<<<dim3(1024 / 64, 1024 / 64), 256, 0, stream>>>(w_proj, wprojT, 1024, 1024, 0, 0, 1.f);
  tcast_k<<<dim3(4096 / 64, 1024 / 64), 256, 0, stream>>>(w_mlp1, wmlp1T, 1024, 4096, 0, 0, 1.f);
  tcast_k<<<dim3(1024 / 64, 4096 / 64), 256, 0, stream>>>(w_mlp2, wmlp2T, 4096, 1024, 0, 0, 1.f);
  lnmod_k<<<8192, 256, 0, stream>>>(x, cmod, 0, 1024, xmod);
  gemm_k<0><<<dim3(3072 / 128, 8192 / 128), 256, 0, stream>>>(
      xmod, wqkvT, 3072, 1024, nullptr, nullptr, nullptr, qkv);
  tv_k<<<dim3(128, 16), 256, 0, stream>>>(qkv, vt);
  attn_k<<<dim3(16, 16, 8), 256, 0, stream>>>(qkv, vt, ybuf);
  gemm_k<2><<<dim3(1024 / 128, 8192 / 128), 256, 0, stream>>>(
      ybuf, wprojT, 1024, 1024, b_proj, x, cmod + 2048, x1);
  lnmod_k<<<8192, 256, 0, stream>>>(x1, cmod, 3072, 4096, xmod2);
  gemm_k<1><<<dim3(4096 / 128, 8192 / 128), 256, 0, stream>>>(
      xmod2, wmlp1T, 4096, 1024, b_mlp1, nullptr, nullptr, hbuf);
  gemm_k<2><<<dim3(1024 / 128, 8192 / 128), 256, 0, stream>>>(
      hbuf, wmlp2T, 1024, 4096, b_mlp2, x1, cmod + 5120, out);
}

// Round 4
// 417.327 us; speedup vs baseline: 1.4785x; 1.0422x over previous
//
#include <hip/hip_runtime.h>
#include <stdint.h>

typedef unsigned short u16;
using bf16x8 = __attribute__((ext_vector_type(8))) __bf16;
using f32x4  = __attribute__((ext_vector_type(4))) float;

#define MFMA16(a,b,c) __builtin_amdgcn_mfma_f32_16x16x32_bf16((a),(b),(c),0,0,0)

__device__ __forceinline__ u16 f2bf(float f) {
  union { float f; uint32_t u; } v; v.f = f;
  uint32_t r = v.u + 0x7FFFu + ((v.u >> 16) & 1u);
  return (u16)(r >> 16);
}

// async global->LDS, 16B per lane; lds ptr must be wave-uniform (HW: base + lane*16)
__device__ __forceinline__ void gload_lds16(const void* g, void* l) {
  typedef const __attribute__((address_space(1))) void* gp_t;
  typedef __attribute__((address_space(3))) void* lp_t;
  __builtin_amdgcn_global_load_lds((gp_t)(uintptr_t)g,
                                   (lp_t)(uint32_t)(uintptr_t)l, 16, 0, 0);
}

// ---------------- adaLN stage 1: partial[ks][b][j] = sum_{k in slice} silu(c)[b,k] w[k,j] ----------
__global__ __launch_bounds__(256)
void adaln_part_k(const float* __restrict__ c, const float* __restrict__ w,
                  float* __restrict__ partial) {
  const int jb = blockIdx.x, ks = blockIdx.y;
  const int j = jb * 256 + threadIdx.x;
  __shared__ float sil[8][32];
  {
    int b = threadIdx.x >> 5, kk = threadIdx.x & 31;
    float v = c[b * 1024 + ks * 32 + kk];
    sil[b][kk] = v / (1.f + __expf(-v));
  }
  __syncthreads();
  float acc[8] = {0,0,0,0,0,0,0,0};
#pragma unroll 8
  for (int kk = 0; kk < 32; ++kk) {
    float wv = w[(size_t)(ks * 32 + kk) * 6144 + j];
#pragma unroll
    for (int b = 0; b < 8; ++b) acc[b] += sil[b][kk] * wv;
  }
#pragma unroll
  for (int b = 0; b < 8; ++b)
    partial[((size_t)ks * 8 + b) * 6144 + j] = acc[b];
}

// ---------------- adaLN stage 2 ----------------
__global__ __launch_bounds__(256)
void adaln_red_k(const float* __restrict__ partial, const float* __restrict__ bias,
                 float* __restrict__ cmod) {
  int g = blockIdx.x * 256 + threadIdx.x;    // 0 .. 8*6144-1
  int j = g % 6144;
  float s = bias[j];
#pragma unroll 8
  for (int ks = 0; ks < 32; ++ks)
    s += partial[(size_t)ks * 8 * 6144 + g];
  cmod[g] = s;
}

// ------- weight cast+transpose: fp32 [K][N] -> bf16 [N][K]; cols [lo,hi) scaled -------
__global__ __launch_bounds__(256)
void tcast_k(const float* __restrict__ in, u16* __restrict__ out, int K, int N,
             int lo, int hi, float scale) {
  __shared__ u16 t[64][65];
  int n0 = blockIdx.x * 64, k0 = blockIdx.y * 64;
#pragma unroll
  for (int i = 0; i < 16; ++i) {
    int idx = i * 256 + threadIdx.x;
    int r = idx >> 6, cc = idx & 63;
    float v = in[(size_t)(k0 + r) * N + n0 + cc];
    int n = n0 + cc;
    if (n >= lo && n < hi) v *= scale;
    t[r][cc] = f2bf(v);
  }
  __syncthreads();
#pragma unroll
  for (int i = 0; i < 16; ++i) {
    int idx = i * 256 + threadIdx.x;
    int r = idx >> 6, cc = idx & 63;
    out[(size_t)(n0 + r) * K + k0 + cc] = t[cc][r];
  }
}

// ---------------- LN + modulate -> bf16 ----------------
__global__ __launch_bounds__(256)
void lnmod_k(const float* __restrict__ x, const float* __restrict__ cmod,
             int shift_off, int scale_off, u16* __restrict__ out) {
  int row = blockIdx.x;           // 0..8191
  int b = row >> 10;
  const float4* xr = (const float4*)(x + (size_t)row * 1024);
  float4 v = xr[threadIdx.x];
  float s = v.x + v.y + v.z + v.w;
  float sq = v.x * v.x + v.y * v.y + v.z * v.z + v.w * v.w;
#pragma unroll
  for (int m = 32; m >= 1; m >>= 1) {
    s  += __shfl_xor(s, m);
    sq += __shfl_xor(sq, m);
  }
  __shared__ float ss[4], ssq[4];
  int wave = threadIdx.x >> 6, lane = threadIdx.x & 63;
  if (lane == 0) { ss[wave] = s; ssq[wave] = sq; }
  __syncthreads();
  s  = ss[0] + ss[1] + ss[2] + ss[3];
  sq = ssq[0] + ssq[1] + ssq[2] + ssq[3];
  float mean = s * (1.f / 1024.f);
  float var  = sq * (1.f / 1024.f) - mean * mean;
  float rstd = rsqrtf(var + 1e-6f);
  int col = threadIdx.x * 4;
  const float* sh = cmod + (size_t)b * 6144 + shift_off + col;
  const float* sc = cmod + (size_t)b * 6144 + scale_off + col;
  float xv[4] = {v.x, v.y, v.z, v.w};
  union { u16 o[4]; uint64_t u; } pk;
#pragma unroll
  for (int j = 0; j < 4; ++j)
    pk.o[j] = f2bf((xv[j] - mean) * rstd * (1.f + sc[j]) + sh[j]);
  *(uint64_t*)(out + (size_t)row * 1024 + col) = pk.u;
}

// ---------------- transpose V section of qkv -> vt[b,h,ch,s] bf16 ----------------
__global__ __launch_bounds__(256)
void tv_k(const u16* __restrict__ qkv, u16* __restrict__ vt) {
  __shared__ u16 t[64][65];
  int r0 = blockIdx.x * 64;
  int h = blockIdx.y;
  int b = r0 >> 10;
  int s0 = r0 & 1023;
#pragma unroll
  for (int i = 0; i < 16; ++i) {
    int idx = i * 256 + threadIdx.x;
    int r = idx >> 6, cc = idx & 63;
    t[r][cc] = qkv[(size_t)(r0 + r) * 3072 + 2048 + h * 64 + cc];
  }
  __syncthreads();
#pragma unroll
  for (int i = 0; i < 16; ++i) {
    int idx = i * 256 + threadIdx.x;
    int ch = idx >> 6, scc = idx & 63;
    vt[((size_t)(b * 16 + h) * 64 + ch) * 1024 + s0 + scc] = t[scc][ch];
  }
}

// =========== GEMM v2: BM=256 BN=128 BK=64, 8 waves, 3-buffer counted-vmcnt pipeline ===========
// C[M,N] = A[M,K](bf16) x Bt[N,K](bf16). LDS rows 128B, (r&7) 16B-chunk XOR swizzle
// (inverse-swizzled global source for global_load_lds; swizzled ds_read).
// Steady state: stage tile t+2 during iter t; end-of-iter s_waitcnt vmcnt(6) waits only
// tile t+1's 6 loads -> tile t+2's loads stay in flight across the barrier (T3/T4).
__device__ __forceinline__ float gelu_f(float x) {
  float z = 1.5957691216057308f * (x + 0.044715f * x * x * x);
  return x / (1.f + __expf(-z));
}

template <int EP>
__global__ __launch_bounds__(512, 2)
void gemm_k(const u16* __restrict__ A, const u16* __restrict__ Bt,
            int N, int K,
            const float* __restrict__ bias, const float* __restrict__ resid,
            const float* __restrict__ gate, void* __restrict__ outp) {
  __shared__ __align__(16) u16 Asb[3][256 * 64];
  __shared__ __align__(16) u16 Bsb[3][128 * 64];
  const int bn = blockIdx.x, bm = blockIdx.y;
  const int tid = threadIdx.x;
  const int wave = tid >> 6, lane = tid & 63;
  const int l15 = lane & 15, lhi = lane >> 4;
  const int wr = wave >> 1, wc = wave & 1;   // 4(M) x 2(N) wave grid
  const int nkt = K >> 6;
  const size_t arow0 = (size_t)bm * 256;
  const size_t brow0 = (size_t)bn * 128;

  f32x4 acc[4][4] = {};

  auto stage = [&](int buf, int kt) {
    const u16* ab = A  + arow0 * K + (size_t)kt * 64;
    const u16* bb = Bt + brow0 * K + (size_t)kt * 64;
#pragma unroll
    for (int i = 0; i < 4; ++i) {            // A: 256 rows x 8 chunks = 2048
      int q = i * 512 + tid;
      int r = q >> 3, c = (q & 7) ^ (r & 7);
      gload_lds16(ab + (size_t)r * K + c * 8, &Asb[buf][(i * 8 + wave) * 512]);
    }
#pragma unroll
    for (int i = 0; i < 2; ++i) {            // B: 128 rows x 8 chunks = 1024
      int q = i * 512 + tid;
      int r = q >> 3, c = (q & 7) ^ (r & 7);
      gload_lds16(bb + (size_t)r * K + c * 8, &Bsb[buf][(i * 8 + wave) * 512]);
    }
  };

  stage(0, 0);
  if (nkt > 1) stage(1, 1);
  asm volatile("s_waitcnt vmcnt(6)" ::: "memory");
  __syncthreads();

  for (int t = 0; t < nkt; ++t) {
    const int s = t % 3;
    if (t + 2 < nkt) stage((t + 2) % 3, t + 2);

    bf16x8 af[4][2], bfr[4][2];
#pragma unroll
    for (int m = 0; m < 4; ++m) {
      int r = wr * 64 + m * 16 + l15;
#pragma unroll
      for (int kh = 0; kh < 2; ++kh) {
        int c = (kh * 4 + lhi) ^ (r & 7);
        af[m][kh] = *(const bf16x8*)&Asb[s][r * 64 + c * 8];
      }
    }
#pragma unroll
    for (int n = 0; n < 4; ++n) {
      int r = wc * 64 + n * 16 + l15;
#pragma unroll
      for (int kh = 0; kh < 2; ++kh) {
        int c = (kh * 4 + lhi) ^ (r & 7);
        bfr[n][kh] = *(const bf16x8*)&Bsb[s][r * 64 + c * 8];
      }
    }
    __builtin_amdgcn_s_setprio(1);
#pragma unroll
    for (int kh = 0; kh < 2; ++kh)
#pragma unroll
      for (int m = 0; m < 4; ++m)
#pragma unroll
        for (int n = 0; n < 4; ++n)
          acc[m][n] = MFMA16(af[m][kh], bfr[n][kh], acc[m][n]);
    __builtin_amdgcn_s_setprio(0);

    if (t + 1 < nkt) {
      if (t + 2 < nkt) asm volatile("s_waitcnt vmcnt(6)" ::: "memory");
      else             asm volatile("s_waitcnt vmcnt(0)" ::: "memory");
      __syncthreads();
    }
  }

#pragma unroll
  for (int m = 0; m < 4; ++m) {
    int row = bm * 256 + wr * 64 + m * 16 + lhi * 4;
#pragma unroll
    for (int n = 0; n < 4; ++n) {
      int col = bn * 128 + wc * 64 + n * 16 + l15;
#pragma unroll
      for (int r = 0; r < 4; ++r) {
        int rr = row + r;
        float v = acc[m][n][r];
        if (EP == 0) {
          ((u16*)outp)[(size_t)rr * N + col] = f2bf(v);
        } else if (EP == 1) {
          ((u16*)outp)[(size_t)rr * N + col] = f2bf(gelu_f(v + bias[col]));
        } else {
          float t2 = v + bias[col];
          int b = rr >> 10;
          float res = resid[(size_t)rr * N + col];
          ((float*)outp)[(size_t)rr * N + col] = res + gate[(size_t)b * 6144 + col] * t2;
        }
      }
    }
  }
}

// ---------------- flash attention: block = (q-tile 64, head, batch) ----------------
__global__ __launch_bounds__(256)
void attn_k(const u16* __restrict__ qkv, const u16* __restrict__ vt,
            u16* __restrict__ y) {
  const int qt = blockIdx.x, h = blockIdx.y, b = blockIdx.z;
  const int tid = threadIdx.x, wave = tid >> 6, lane = tid & 63;
  const int l15 = lane & 15, lhi = lane >> 4;
  __shared__ __align__(16) u16 Qs[64 * 64];
  __shared__ __align__(16) u16 Ks[2][64 * 64];
  __shared__ __align__(16) u16 Vs[2][64 * 64];
  __shared__ __align__(16) u16 Ps[64 * 64];
  const size_t qrow0 = (size_t)b * 1024 + qt * 64;
  const size_t krow0 = (size_t)b * 1024;
  const size_t vrow0 = (size_t)(b * 16 + h) * 64;

  auto stageQ = [&]() {
#pragma unroll
    for (int i = 0; i < 2; ++i) {
      int c = (i * 4 + wave) * 64 + lane;
      int r = c >> 3, j = (c & 7) ^ (c >> 3 & 7);
      gload_lds16(qkv + (qrow0 + r) * 3072 + 1024 + h * 64 + j * 8,
                  &Qs[(i * 4 + wave) * 512]);
    }
  };
  auto stageKV = [&](int buf, int kt) {
#pragma unroll
    for (int i = 0; i < 2; ++i) {
      int c = (i * 4 + wave) * 64 + lane;
      int r = c >> 3, j = (c & 7) ^ (c >> 3 & 7);
      gload_lds16(qkv + (krow0 + kt * 64 + r) * 3072 + h * 64 + j * 8,
                  &Ks[buf][(i * 4 + wave) * 512]);
      gload_lds16(vt + (vrow0 + r) * 1024 + kt * 64 + j * 8,
                  &Vs[buf][(i * 4 + wave) * 512]);
    }
  };
  auto ldb = [](const u16* base, int row, int cc) -> bf16x8 {
    return *(const bf16x8*)&base[row * 64 + ((cc ^ (row & 7)) << 3)];
  };

  stageQ();
  stageKV(0, 0);
  __syncthreads();
  bf16x8 qf[2];
  qf[0] = ldb(Qs, wave * 16 + l15, lhi);
  qf[1] = ldb(Qs, wave * 16 + l15, 4 + lhi);

  bf16x8 ones;
#pragma unroll
  for (int j = 0; j < 8; ++j) ones[j] = (__bf16)1.0f;

  float m_r[4];
  f32x4 o[5] = {};   // o[4] = softmax denominator (ones-column MFMA)
#pragma unroll
  for (int r = 0; r < 4; ++r) m_r[r] = -3.0e38f;

  for (int kt = 0; kt < 16; ++kt) {
    int cur = kt & 1;
    if (kt < 15) stageKV(cur ^ 1, kt + 1);
    f32x4 sf[4] = {};
    __builtin_amdgcn_s_setprio(1);
#pragma unroll
    for (int n = 0; n < 4; ++n) {
      bf16x8 k0 = ldb(Ks[cur], n * 16 + l15, lhi);
      bf16x8 k1 = ldb(Ks[cur], n * 16 + l15, 4 + lhi);
      sf[n] = MFMA16(qf[0], k0, sf[n]);
      sf[n] = MFMA16(qf[1], k1, sf[n]);
    }
    __builtin_amdgcn_s_setprio(0);
#pragma unroll
    for (int r = 0; r < 4; ++r) {
      float mx = fmaxf(fmaxf(sf[0][r], sf[1][r]), fmaxf(sf[2][r], sf[3][r]));
      mx = fmaxf(mx, __shfl_xor(mx, 1));
      mx = fmaxf(mx, __shfl_xor(mx, 2));
      mx = fmaxf(mx, __shfl_xor(mx, 4));
      mx = fmaxf(mx, __shfl_xor(mx, 8));
      float mn = fmaxf(m_r[r], mx);
      float al = __expf(m_r[r] - mn);
      m_r[r] = mn;
      float p0 = __expf(sf[0][r] - mn);
      float p1 = __expf(sf[1][r] - mn);
      float p2 = __expf(sf[2][r] - mn);
      float p3 = __expf(sf[3][r] - mn);
      o[0][r] *= al; o[1][r] *= al; o[2][r] *= al; o[3][r] *= al; o[4][r] *= al;
      int row = wave * 16 + lhi * 4 + r;
      int rb = row * 64, sw = (row & 7) << 3;
      Ps[rb + (l15 ^ sw)]        = f2bf(p0);
      Ps[rb + ((l15 + 16) ^ sw)] = f2bf(p1);
      Ps[rb + ((l15 + 32) ^ sw)] = f2bf(p2);
      Ps[rb + ((l15 + 48) ^ sw)] = f2bf(p3);
    }
    bf16x8 pf0 = ldb(Ps, wave * 16 + l15, lhi);
    bf16x8 pf1 = ldb(Ps, wave * 16 + l15, 4 + lhi);
    __builtin_amdgcn_s_setprio(1);
#pragma unroll
    for (int n = 0; n < 4; ++n) {
      bf16x8 v0 = ldb(Vs[cur], n * 16 + l15, lhi);
      bf16x8 v1 = ldb(Vs[cur], n * 16 + l15, 4 + lhi);
      o[n] = MFMA16(pf0, v0, o[n]);
      o[n] = MFMA16(pf1, v1, o[n]);
    }
    o[4] = MFMA16(pf0, ones, o[4]);
    o[4] = MFMA16(pf1, ones, o[4]);
    __builtin_amdgcn_s_setprio(0);
    __syncthreads();
  }
#pragma unroll
  for (int r = 0; r < 4; ++r) {
    float inv = 1.0f / o[4][r];
    size_t yrow = (qrow0 + wave * 16 + lhi * 4 + r) * 1024 + h * 64 + l15;
    y[yrow]      = f2bf(o[0][r] * inv);
    y[yrow + 16] = f2bf(o[1][r] * inv);
    y[yrow + 32] = f2bf(o[2][r] * inv);
    y[yrow + 48] = f2bf(o[3][r] * inv);
  }
}

// ---------------- host ----------------
extern "C" void kernel_launch(void* const* d_in, const int* in_sizes, int n_in,
                              void* d_out, int out_size, void* d_ws, size_t ws_size,
                              hipStream_t stream) {
  const float* x      = (const float*)d_in[0];
  const float* c      = (const float*)d_in[1];
  const float* w_ada  = (const float*)d_in[2];
  const float* b_ada  = (const float*)d_in[3];
  const float* w_qkv  = (const float*)d_in[4];
  const float* w_proj = (const float*)d_in[5];
  const float* b_proj = (const float*)d_in[6];
  const float* w_mlp1 = (const float*)d_in[7];
  const float* b_mlp1 = (const float*)d_in[8];
  const float* w_mlp2 = (const float*)d_in[9];
  const float* b_mlp2 = (const float*)d_in[10];
  float* out = (float*)d_out;

  char* ws = (char*)d_ws;
  size_t off = 0;
  auto alloc = [&](size_t bytes) {
    void* p = ws + off;
    off += (bytes + 255) & ~(size_t)255;
    return p;
  };
  float* cmod  = (float*)alloc((size_t)8 * 6144 * 4);
  float* apart = (float*)alloc((size_t)32 * 8 * 6144 * 4);
  u16* wqkvT   = (u16*)alloc((size_t)3072 * 1024 * 2);
  u16* wprojT  = (u16*)alloc((size_t)1024 * 1024 * 2);
  u16* wmlp1T  = (u16*)alloc((size_t)4096 * 1024 * 2);
  u16* wmlp2T  = (u16*)alloc((size_t)1024 * 4096 * 2);
  u16* xmod    = (u16*)alloc((size_t)8192 * 1024 * 2);   // reused as attention out y
  u16* qkv     = (u16*)alloc((size_t)8192 * 3072 * 2);   // front reused as x_mod2
  u16* vt      = (u16*)alloc((size_t)8 * 16 * 64 * 1024 * 2);
  float* x1    = (float*)alloc((size_t)8192 * 1024 * 4);
  u16* hbuf    = (u16*)alloc((size_t)8192 * 4096 * 2);
  u16* ybuf  = xmod;   // x_mod dead after qkv GEMM
  u16* xmod2 = qkv;    // qkv dead after attention

  adaln_part_k<<<dim3(24, 32), 256, 0, stream>>>(c, w_ada, apart);
  adaln_red_k<<<192, 256, 0, stream>>>(apart, b_ada, cmod);
  tcast_k<<<dim3(3072 / 64, 1024 / 64), 256, 0, stream>>>(w_qkv,  wqkvT,  1024, 3072,
                                                          1024, 2048, 1.0f / 64.0f);
  tcast_k<<<dim3(1024 / 64, 1024 / 64), 256, 0, stream>>>(w_proj, wprojT, 1024, 1024, 0, 0, 1.f);
  tcast_k<<<dim3(4096 / 64, 1024 / 64), 256, 0, stream>>>(w_mlp1, wmlp1T, 1024, 4096, 0, 0, 1.f);
  tcast_k<<<dim3(1024 / 64, 4096 / 64), 256, 0, stream>>>(w_mlp2, wmlp2T, 4096, 1024, 0, 0, 1.f);
  lnmod_k<<<8192, 256, 0, stream>>>(x, cmod, 0, 1024, xmod);
  gemm_k<0><<<dim3(3072 / 128, 8192 / 256), 512, 0, stream>>>(
      xmod, wqkvT, 3072, 1024, nullptr, nullptr, nullptr, qkv);
  tv_k<<<dim3(128, 16), 256, 0, stream>>>(qkv, vt);
  attn_k<<<dim3(16, 16, 8), 256, 0, stream>>>(qkv, vt, ybuf);
  gemm_k<2><<<dim3(1024 / 128, 8192 / 256), 512, 0, stream>>>(
      ybuf, wprojT, 1024, 1024, b_proj, x, cmod + 2048, x1);
  lnmod_k<<<8192, 256, 0, stream>>>(x1, cmod, 3072, 4096, xmod2);
  gemm_k<1><<<dim3(4096 / 128, 8192 / 256), 512, 0, stream>>>(
      xmod2, wmlp1T, 4096, 1024, b_mlp1, nullptr, nullptr, hbuf);
  gemm_k<2><<<dim3(1024 / 128, 8192 / 256), 512, 0, stream>>>(
      hbuf, wmlp2T, 1024, 4096, b_mlp2, x1, cmod + 5120, out);
}